// Round 13
// baseline (795.108 us; speedup 1.0000x reference)
//
#include <hip/hip_runtime.h>
#include <hip/hip_bf16.h>
#include <math.h>

// ---------------------------------------------------------------------------
// GAT edge classifier. Pipeline per call:
//   weight prep (1 kernel), CSR build with x8-padded runs + degree-bucketed
//   node order (count/scan/XCD-class scatter), emb MFMA-GEMM ->
//   3x [ MFMA-GEMM(+el/er) -> edge_prep -> branch-free aggregate ] -> score
// h is bf16 at every inter-layer boundary; all accumulation fp32.
// order[] groups equal-trip-count nodes into the same waves -> minimal
// exec-mask waste in the 16-lane-group kernels (exact permutation).
// ---------------------------------------------------------------------------

constexpr float SLOPE = 0.2f;

typedef __attribute__((ext_vector_type(8))) short bf16x8;
typedef __attribute__((ext_vector_type(4))) float f32x4;

__device__ __forceinline__ float b2f(unsigned short u) {
  union { unsigned int i; float f; } v;
  v.i = ((unsigned int)u) << 16;
  return v.f;
}
__device__ __forceinline__ unsigned short f2b(float f) {
  unsigned int x = __float_as_uint(f);
  unsigned int r = (x + 0x7fffu + ((x >> 16) & 1u)) >> 16;   // RNE
  return (unsigned short)r;
}

// ---- weight prep: 4 matrices W[K=128][M] fp32 -> Wt[M][128] bf16, fused ---
__global__ void prep_wt_all(const float* __restrict__ Wa,
                            const float* __restrict__ Wb,
                            const float* __restrict__ Wc,
                            const float* __restrict__ Wd,
                            unsigned short* __restrict__ Ta,
                            unsigned short* __restrict__ Tb,
                            unsigned short* __restrict__ Tc,
                            unsigned short* __restrict__ Td) {
  int i = blockIdx.x * 256 + threadIdx.x;
  const float* W; unsigned short* T; int M; int off;
  if (i < 16384)      { W = Wa; T = Ta; M = 128; off = i; }
  else if (i < 32768) { W = Wb; T = Tb; M = 128; off = i - 16384; }
  else if (i < 49152) { W = Wc; T = Tc; M = 128; off = i - 32768; }
  else if (i < 57344) { W = Wd; T = Td; M = 64;  off = i - 49152; }
  else return;
  int k = off / M, m = off - k * M;
  T[m * 128 + k] = f2b(W[off]);
}

// ---------- MFMA GEMM: Y = X[N,128] @ W[128,M] (+bias) [+ el/er] -----------
template<int M, bool AF32>
__global__ __launch_bounds__(256)
void gemm_mfma(const void* __restrict__ Xv,
               const unsigned short* __restrict__ Wt,
               const float* __restrict__ bias,
               const float* __restrict__ al, const float* __restrict__ ar,
               unsigned short* __restrict__ Yb,
               float* __restrict__ el, float* __restrict__ er, int N) {
  constexpr int NT = M / 16;               // 8 (M=128) or 4 (M=64)
  constexpr int H = M / 64;

  const int tid = threadIdx.x;
  const int wave = tid >> 6;
  const int lane = tid & 63;
  const int r = lane & 15;                 // A row / B col / C col
  const int kg = lane >> 4;                // k-group 0..3
  const int rowbase = blockIdx.x * 64 + wave * 16;
  int grow = rowbase + r;
  int growc = grow < N ? grow : N - 1;

  f32x4 acc[NT];
  #pragma unroll
  for (int t = 0; t < NT; ++t) acc[t] = (f32x4){0.f, 0.f, 0.f, 0.f};

  #pragma unroll
  for (int kk = 0; kk < 4; ++kk) {
    const int k0 = kk * 32 + kg * 8;
    bf16x8 a;
    if constexpr (AF32) {
      const float* X = (const float*)Xv;
      const float4* xp =
          reinterpret_cast<const float4*>(X + (size_t)growc * 128 + k0);
      float4 x0 = xp[0], x1 = xp[1];
      a[0] = (short)f2b(x0.x); a[1] = (short)f2b(x0.y);
      a[2] = (short)f2b(x0.z); a[3] = (short)f2b(x0.w);
      a[4] = (short)f2b(x1.x); a[5] = (short)f2b(x1.y);
      a[6] = (short)f2b(x1.z); a[7] = (short)f2b(x1.w);
    } else {
      const unsigned short* Xb = (const unsigned short*)Xv;
      a = *reinterpret_cast<const bf16x8*>(Xb + (size_t)growc * 128 + k0);
    }
    #pragma unroll
    for (int t = 0; t < NT; ++t) {
      bf16x8 b = *reinterpret_cast<const bf16x8*>(
          Wt + (size_t)(t * 16 + r) * 128 + k0);
      acc[t] = __builtin_amdgcn_mfma_f32_16x16x32_bf16(a, b, acc[t], 0, 0, 0);
    }
  }

  float bv[NT];
  #pragma unroll
  for (int t = 0; t < NT; ++t) bv[t] = bias ? bias[t * 16 + r] : 0.f;
  float alv[NT], arv[NT];
  if (al != nullptr) {
    #pragma unroll
    for (int t = 0; t < NT; ++t) {
      alv[t] = al[t * 16 + r];
      arv[t] = ar[t * 16 + r];
    }
  }

  #pragma unroll
  for (int j = 0; j < 4; ++j) {
    int orow = rowbase + kg * 4 + j;       // C row for this (kg, j)
    bool ok = orow < N;
    if (ok) {
      #pragma unroll
      for (int t = 0; t < NT; ++t)
        Yb[(size_t)orow * M + t * 16 + r] = f2b(acc[t][j] + bv[t]);
    }
    if (al != nullptr) {
      float pl0 = 0.f, pr0 = 0.f, pl1 = 0.f, pr1 = 0.f;
      #pragma unroll
      for (int t = 0; t < 4; ++t) {
        pl0 += acc[t][j] * alv[t];
        pr0 += acc[t][j] * arv[t];
      }
      if constexpr (H == 2) {
        #pragma unroll
        for (int t = 4; t < 8; ++t) {
          pl1 += acc[t][j] * alv[t];
          pr1 += acc[t][j] * arv[t];
        }
      }
      #pragma unroll
      for (int off = 1; off < 16; off <<= 1) {   // within 16-lane group
        pl0 += __shfl_xor(pl0, off);
        pr0 += __shfl_xor(pr0, off);
        if constexpr (H == 2) {
          pl1 += __shfl_xor(pl1, off);
          pr1 += __shfl_xor(pr1, off);
        }
      }
      if (r == 0 && ok) {
        if constexpr (H == 2) {
          el[orow * 2 + 0] = pl0; el[orow * 2 + 1] = pl1;
          er[orow * 2 + 0] = pr0; er[orow * 2 + 1] = pr1;
        } else {
          el[orow] = pl0;
          er[orow] = pr0;
        }
      }
    }
  }
}

// ------------------------------ CSR build ----------------------------------
// XCD-class-partitioned count: cnt-line atomics from one XCD only.
__global__ __launch_bounds__(256)
void count_dst(const int* __restrict__ dst, int* __restrict__ cnt, int E) {
  int cls = blockIdx.x & 7;
  int grp = blockIdx.x >> 3;
  int nGrp = gridDim.x >> 3;
  for (int base = grp * 256; base < E; base += nGrp * 256) {
    int i = base + threadIdx.x;
    if (i < E) {
      int d = dst[i];
      if (((d >> 4) & 7) == cls) atomicAdd(&cnt[d], 1);
    }
  }
}

// scan over PADDED counts ((deg+7)&~7) + trip-bin histogram (binCnt[64])
__global__ void scan1(const int* __restrict__ cnt, int* __restrict__ outv,
                      int* __restrict__ bsum, int* __restrict__ binCnt,
                      int n) {
  __shared__ int sm[256];
  int tid = threadIdx.x;
  int base = blockIdx.x * 1024 + tid * 4;
  int pre[4];
  int s = 0;
  #pragma unroll
  for (int j = 0; j < 4; ++j) {
    int idx = base + j;
    int c = (idx < n) ? cnt[idx] : 0;
    int v = (idx < n) ? ((c + 7) & ~7) : 0;
    if (idx < n) {
      int t = (c + 7) >> 3; if (t > 63) t = 63;
      atomicAdd(&binCnt[t], 1);
    }
    pre[j] = s;
    s += v;
  }
  sm[tid] = s;
  __syncthreads();
  for (int off = 1; off < 256; off <<= 1) {
    int a = (tid >= off) ? sm[tid - off] : 0;
    __syncthreads();
    sm[tid] += a;
    __syncthreads();
  }
  int excl = sm[tid] - s;
  #pragma unroll
  for (int j = 0; j < 4; ++j) {
    int idx = base + j;
    if (idx < n) outv[idx] = excl + pre[j];
  }
  if (tid == 255) bsum[blockIdx.x] = sm[255];
}

// serial: block-sum scan + 64-bin exclusive scan -> binCur
__global__ void scan2(const int* __restrict__ bsum, int* __restrict__ btop,
                      int nb, int* __restrict__ row_last,
                      const int* __restrict__ binCnt,
                      int* __restrict__ binCur) {
  if (threadIdx.x == 0 && blockIdx.x == 0) {
    int s = 0;
    for (int i = 0; i < nb; ++i) { btop[i] = s; s += bsum[i]; }
    *row_last = s;
    int s2 = 0;
    for (int i = 0; i < 64; ++i) { binCur[i] = s2; s2 += binCnt[i]; }
  }
}

// finalize rp/cur + scatter degree-bucketed node order (wave-aggregated
// atomics: one atomicAdd per distinct bin per wave)
__global__ void scan3(int* __restrict__ rp, int* __restrict__ cur,
                      const int* __restrict__ btop,
                      const int* __restrict__ cnt, int* __restrict__ binCur,
                      int* __restrict__ order, int n) {
  int i = blockIdx.x * blockDim.x + threadIdx.x;
  int lane = threadIdx.x & 63;
  bool live = i < n;
  int t = 0;
  if (live) {
    int v = rp[i] + btop[i >> 10];
    rp[i] = v;
    cur[i] = v;
    int c = cnt[i];
    t = (c + 7) >> 3; if (t > 63) t = 63;
  }
  // wave-aggregated order scatter
  int pos = 0;
  bool done = !live;
  unsigned long long remaining = __ballot(!done);
  while (remaining) {
    int srcl = __ffsll((long long)remaining) - 1;
    int tl = __shfl(t, srcl);
    unsigned long long same = __ballot(!done && t == tl);
    if (!done && t == tl) {
      int lead = __ffsll((long long)same) - 1;
      int cnt_ = __popcll(same);
      int basep = 0;
      if (lane == lead) basep = atomicAdd(&binCur[tl], cnt_);
      basep = __shfl(basep, lead);
      pos = basep + __popcll(same & ((1ull << lane) - 1ull));
      done = true;
    }
    remaining &= ~same;
  }
  if (live) order[pos] = i;
}

// XCD-class-partitioned scatter. After this, cur[node] = real end of run.
__global__ __launch_bounds__(256)
void scatter_edges(const int* __restrict__ src, const int* __restrict__ dst,
                   int* __restrict__ cur, int* __restrict__ s_csr, int E) {
  int cls = blockIdx.x & 7;
  int grp = blockIdx.x >> 3;
  int nGrp = gridDim.x >> 3;
  for (int base = grp * 256; base < E; base += nGrp * 256) {
    int i = base + threadIdx.x;
    if (i < E) {
      int d = dst[i];
      if (((d >> 4) & 7) == cls) {
        int p = atomicAdd(&cur[d], 1);
        s_csr[p] = src[i];
      }
    }
  }
}

// ---- per-node-run edge records: edat[h*EP + p] = (exp(leaky), src) --------
// nodes processed in degree-bucketed order; pad slots get (0,0).
template<int H>
__global__ __launch_bounds__(256)
void edge_prep(const int* __restrict__ s_csr, const float* __restrict__ el,
               const float* __restrict__ er, const int* __restrict__ rp,
               const int* __restrict__ ends, const int* __restrict__ order,
               float2* __restrict__ edat, int N, int EP) {
  int tid = threadIdx.x;
  int g = blockIdx.x * 16 + (tid >> 4);
  int sl = tid & 15;
  if (g >= N) return;
  int node = order[g];
  int beg = rp[node];
  int rend = ends[node];                   // real end
  int pend = rp[node + 1];                 // padded end
  if constexpr (H == 2) {
    float2 re = reinterpret_cast<const float2*>(er)[node];
    for (int p = beg + sl; p < rend; p += 16) {
      int s = s_csr[p];
      float2 le = reinterpret_cast<const float2*>(el)[s];
      float e0 = le.x + re.x;
      float e1 = le.y + re.y;
      e0 = e0 > 0.f ? e0 : SLOPE * e0;
      e1 = e1 > 0.f ? e1 : SLOPE * e1;
      float sb = __int_as_float(s);
      edat[p] = make_float2(__expf(e0), sb);
      edat[(size_t)EP + p] = make_float2(__expf(e1), sb);
    }
    int p2 = rend + sl;
    if (p2 < pend) {                       // pad slots (<=7)
      edat[p2] = make_float2(0.f, __int_as_float(0));
      edat[(size_t)EP + p2] = make_float2(0.f, __int_as_float(0));
    }
  } else {
    float re = er[node];
    for (int p = beg + sl; p < rend; p += 16) {
      int s = s_csr[p];
      float ev = el[s] + re;
      ev = ev > 0.f ? ev : SLOPE * ev;
      edat[p] = make_float2(__expf(ev), __int_as_float(s));
    }
    int p2 = rend + sl;
    if (p2 < pend) edat[p2] = make_float2(0.f, __int_as_float(0));
  }
}

// ------- fused edge-softmax aggregation + bias + elu (branch-free) ---------
// 16-lane group per (sorted-slot, head); runs x8-padded -> no bounds checks.
template<int H, bool SCORE>
__global__ __launch_bounds__(256)
void gat_aggregate(const unsigned short* __restrict__ featb,
                   const float2* __restrict__ edat,
                   const float* __restrict__ bias,
                   const int* __restrict__ row_ptr,
                   const int* __restrict__ order,
                   unsigned short* __restrict__ houtb,
                   const float* __restrict__ Wsc,
                   float* __restrict__ ps, float* __restrict__ pd,
                   int N, int EP) {
  int tid = threadIdx.x;
  int pid = blockIdx.x * 16 + (tid >> 4);  // (slot,head) pair id
  int sl = tid & 15;
  const int NH = N * H;
  bool live = pid < NH;
  int pc = live ? pid : 0;
  int node, head;
  if constexpr (H == 2) { node = order[pc >> 1]; head = pc & 1; }
  else                  { node = order[pc];      head = 0; }
  int beg = live ? row_ptr[node] : 0;
  int end = live ? row_ptr[node + 1] : 0;

  const int rowoff = head * 64 + sl * 4;   // bf16 elem offset within row
  const float2* edath = edat + (size_t)head * EP;

  float4 acc = make_float4(0.f, 0.f, 0.f, 0.f);
  float den = 0.f;

  for (int p = beg; p < end; p += 8) {
    #pragma unroll
    for (int j = 0; j < 8; ++j) {
      float2 ed = edath[p + j];
      float ex = ed.x;
      int s = __float_as_int(ed.y);
      ushort4 u = *reinterpret_cast<const ushort4*>(
          &featb[(size_t)s * (H * 64) + rowoff]);
      den += ex;
      acc.x += ex * b2f(u.x);
      acc.y += ex * b2f(u.y);
      acc.z += ex * b2f(u.z);
      acc.w += ex * b2f(u.w);
    }
  }

  if (live) {
    float inv = 1.f / (den > 0.f ? den : 1.f);
    float4 bv = reinterpret_cast<const float4*>(bias)[head * 16 + sl];
    float4 r;
    r.x = acc.x * inv + bv.x;
    r.y = acc.y * inv + bv.y;
    r.z = acc.z * inv + bv.z;
    r.w = acc.w * inv + bv.w;
    r.x = r.x > 0.f ? r.x : expm1f(r.x);
    r.y = r.y > 0.f ? r.y : expm1f(r.y);
    r.z = r.z > 0.f ? r.z : expm1f(r.z);
    r.w = r.w > 0.f ? r.w : expm1f(r.w);

    if constexpr (!SCORE) {
      ushort4 o;
      o.x = f2b(r.x); o.y = f2b(r.y); o.z = f2b(r.z); o.w = f2b(r.w);
      *reinterpret_cast<ushort4*>(
          &houtb[((size_t)node * H + head) * 64 + sl * 4]) = o;
    } else {
      float s0 = r.x * Wsc[(4 * sl + 0) * 2] + r.y * Wsc[(4 * sl + 1) * 2] +
                 r.z * Wsc[(4 * sl + 2) * 2] + r.w * Wsc[(4 * sl + 3) * 2];
      float s1 = r.x * Wsc[(4 * sl + 0) * 2 + 1] + r.y * Wsc[(4 * sl + 1) * 2 + 1] +
                 r.z * Wsc[(4 * sl + 2) * 2 + 1] + r.w * Wsc[(4 * sl + 3) * 2 + 1];
      float d0 = r.x * Wsc[(64 + 4 * sl + 0) * 2] + r.y * Wsc[(64 + 4 * sl + 1) * 2] +
                 r.z * Wsc[(64 + 4 * sl + 2) * 2] + r.w * Wsc[(64 + 4 * sl + 3) * 2];
      float d1 = r.x * Wsc[(64 + 4 * sl + 0) * 2 + 1] + r.y * Wsc[(64 + 4 * sl + 1) * 2 + 1] +
                 r.z * Wsc[(64 + 4 * sl + 2) * 2 + 1] + r.w * Wsc[(64 + 4 * sl + 3) * 2 + 1];
      #pragma unroll
      for (int off = 1; off < 16; off <<= 1) {   // stays inside 16-lane group
        s0 += __shfl_xor(s0, off);
        s1 += __shfl_xor(s1, off);
        d0 += __shfl_xor(d0, off);
        d1 += __shfl_xor(d1, off);
      }
      if (sl == 0) {
        ps[node * 2 + 0] = s0;
        ps[node * 2 + 1] = s1;
        pd[node * 2 + 0] = d0;
        pd[node * 2 + 1] = d1;
      }
    }
  }
}

// ----------------------- edge scorer output --------------------------------
__global__ void score_out(const int* __restrict__ src,
                          const int* __restrict__ dst,
                          const float* __restrict__ ps,
                          const float* __restrict__ pd,
                          const float* __restrict__ bs,
                          float* __restrict__ out, int E) {
  int i = blockIdx.x * blockDim.x + threadIdx.x;
  if (i < E) {
    int s = src[i], d = dst[i];
    float2 a = *reinterpret_cast<const float2*>(ps + (size_t)s * 2);
    float2 b = *reinterpret_cast<const float2*>(pd + (size_t)d * 2);
    float2 o;
    o.x = a.x + b.x + bs[0];
    o.y = a.y + b.y + bs[1];
    *reinterpret_cast<float2*>(out + (size_t)i * 2) = o;
  }
}

// ---------------------------------------------------------------------------
extern "C" void kernel_launch(void* const* d_in, const int* in_sizes, int n_in,
                              void* d_out, int out_size, void* d_ws,
                              size_t ws_size, hipStream_t stream) {
  const float* x    = (const float*)d_in[0];
  const int*   src  = (const int*)d_in[1];
  const int*   dst  = (const int*)d_in[2];
  const float* Wemb = (const float*)d_in[3];
  const float* bemb = (const float*)d_in[4];
  const float* W0   = (const float*)d_in[5];
  const float* al0  = (const float*)d_in[6];
  const float* ar0  = (const float*)d_in[7];
  const float* b0   = (const float*)d_in[8];
  const float* W1   = (const float*)d_in[9];
  const float* al1  = (const float*)d_in[10];
  const float* ar1  = (const float*)d_in[11];
  const float* b1   = (const float*)d_in[12];
  const float* W2   = (const float*)d_in[13];
  const float* al2  = (const float*)d_in[14];
  const float* ar2  = (const float*)d_in[15];
  const float* b2   = (const float*)d_in[16];
  const float* Wsc  = (const float*)d_in[17];
  const float* bsc  = (const float*)d_in[18];

  const int N = in_sizes[0] / 128;
  const int E = in_sizes[1];
  float* out = (float*)d_out;
  const int EP = E + 7 * N + 8;            // upper bound on padded edge count

  // workspace carve-up (16B-aligned buffers first)
  char* w = (char*)d_ws;
  float2* edat = (float2*)w; w += (size_t)EP * 2 * 8;    // per-head (ex, src)
  unsigned short* Ab = (unsigned short*)w; w += (size_t)N * 128 * 2; // bf16 h
  unsigned short* Bb = (unsigned short*)w; w += (size_t)N * 128 * 2; // bf16 feat
  unsigned short* WembT = (unsigned short*)w; w += 128 * 128 * 2;
  unsigned short* W0T   = (unsigned short*)w; w += 128 * 128 * 2;
  unsigned short* W1T   = (unsigned short*)w; w += 128 * 128 * 2;
  unsigned short* W2T   = (unsigned short*)w; w += 128 * 64 * 2;
  float* el  = (float*)w; w += (size_t)N * 2 * 4;
  float* er  = (float*)w; w += (size_t)N * 2 * 4;
  float* ps  = (float*)w; w += (size_t)N * 2 * 4;
  float* pd  = (float*)w; w += (size_t)N * 2 * 4;
  int* s_csr = (int*)w;   w += (size_t)EP * 4;
  int* cnt   = (int*)w;   w += (size_t)N * 4;
  int* binCnt = (int*)w;  w += 64 * 4;                   // memset with cnt
  int* rp    = (int*)w;   w += (size_t)(N + 4) * 4;
  int* cur   = (int*)w;   w += (size_t)N * 4;
  int* order = (int*)w;   w += (size_t)N * 4;
  int* binCur = (int*)w;  w += 64 * 4;
  int* bsum  = (int*)w;   w += 4096;
  int* btop  = (int*)w;   w += 4096;

  // ---- weight prep (bf16 transposed, one dispatch) ----
  prep_wt_all<<<(57344 + 255) / 256, 256, 0, stream>>>(
      Wemb, W0, W1, W2, WembT, W0T, W1T, W2T);

  // ---- CSR build (by dst), x8-padded runs + degree-bucketed order ----
  hipMemsetAsync(cnt, 0, (size_t)N * 4 + 64 * 4, stream);  // cnt + binCnt
  count_dst<<<2048, 256, 0, stream>>>(dst, cnt, E);
  int nb = (N + 1023) / 1024;
  scan1<<<nb, 256, 0, stream>>>(cnt, rp, bsum, binCnt, N);
  scan2<<<1, 64, 0, stream>>>(bsum, btop, nb, rp + N, binCnt, binCur);
  scan3<<<(N + 255) / 256, 256, 0, stream>>>(rp, cur, btop, cnt, binCur,
                                             order, N);
  scatter_edges<<<2048, 256, 0, stream>>>(src, dst, cur, s_csr, E);

  const int gb = (N + 63) / 64;        // MFMA GEMM blocks (64 rows each)
  const int nbk = (N + 15) / 16;       // per-node-run kernels
  const int pb2 = (N * 2 + 15) / 16;   // pair blocks, H=2
  const int pb1 = (N * 1 + 15) / 16;

  // ---- embedding: x(fp32) @ Wemb + bemb -> Ab (bf16) ----
  gemm_mfma<128, true><<<gb, 256, 0, stream>>>(x, WembT, bemb, nullptr,
                                               nullptr, Ab, nullptr, nullptr,
                                               N);

  // ---- GAT layer 0 ----
  gemm_mfma<128, false><<<gb, 256, 0, stream>>>(Ab, W0T, nullptr, al0, ar0,
                                                Bb, el, er, N);
  edge_prep<2><<<nbk, 256, 0, stream>>>(s_csr, el, er, rp, cur, order, edat,
                                        N, EP);
  gat_aggregate<2, false><<<pb2, 256, 0, stream>>>(Bb, edat, b0, rp, order,
                                                   Ab, nullptr, nullptr,
                                                   nullptr, N, EP);
  // ---- GAT layer 1 ----
  gemm_mfma<128, false><<<gb, 256, 0, stream>>>(Ab, W1T, nullptr, al1, ar1,
                                                Bb, el, er, N);
  edge_prep<2><<<nbk, 256, 0, stream>>>(s_csr, el, er, rp, cur, order, edat,
                                        N, EP);
  gat_aggregate<2, false><<<pb2, 256, 0, stream>>>(Bb, edat, b1, rp, order,
                                                   Ab, nullptr, nullptr,
                                                   nullptr, N, EP);
  // ---- GAT layer 2 (1 head) + fused scorer partials ----
  gemm_mfma<64, false><<<gb, 256, 0, stream>>>(Ab, W2T, nullptr, al2, ar2,
                                               Bb, el, er, N);
  edge_prep<1><<<nbk, 256, 0, stream>>>(s_csr, el, er, rp, cur, order, edat,
                                        N, EP);
  gat_aggregate<1, true><<<pb1, 256, 0, stream>>>(Bb, edat, b2, rp, order,
                                                  nullptr, Wsc, ps, pd,
                                                  N, EP);

  // ---- edge scorer output ----
  score_out<<<(E + 255) / 256, 256, 0, stream>>>(src, dst, ps, pd, bsc, out, E);
}

// Round 14
// 419.536 us; speedup vs baseline: 1.8952x; 1.8952x over previous
//
#include <hip/hip_runtime.h>
#include <hip/hip_bf16.h>
#include <math.h>

// ---------------------------------------------------------------------------
// GAT edge classifier. Pipeline per call:
//   weight prep (1 kernel), CSR build with x8-padded runs + degree-bucketed
//   node order (count/scan/XCD-class scatter), emb MFMA-GEMM ->
//   3x [ MFMA-GEMM(+el/er) -> edge_prep -> branch-free aggregate ] -> score
// h is bf16 at every inter-layer boundary; all accumulation fp32.
// order[] groups equal-trip-count nodes into the same waves -> minimal
// exec-mask waste in the 16-lane-group kernels (exact permutation).
// scan1 histogram uses per-block LDS aggregation (round-13 lesson: 50K
// same-address global atomics serialize -> 377us; Guideline 12).
// ---------------------------------------------------------------------------

constexpr float SLOPE = 0.2f;

typedef __attribute__((ext_vector_type(8))) short bf16x8;
typedef __attribute__((ext_vector_type(4))) float f32x4;

__device__ __forceinline__ float b2f(unsigned short u) {
  union { unsigned int i; float f; } v;
  v.i = ((unsigned int)u) << 16;
  return v.f;
}
__device__ __forceinline__ unsigned short f2b(float f) {
  unsigned int x = __float_as_uint(f);
  unsigned int r = (x + 0x7fffu + ((x >> 16) & 1u)) >> 16;   // RNE
  return (unsigned short)r;
}

// ---- weight prep: 4 matrices W[K=128][M] fp32 -> Wt[M][128] bf16, fused ---
__global__ void prep_wt_all(const float* __restrict__ Wa,
                            const float* __restrict__ Wb,
                            const float* __restrict__ Wc,
                            const float* __restrict__ Wd,
                            unsigned short* __restrict__ Ta,
                            unsigned short* __restrict__ Tb,
                            unsigned short* __restrict__ Tc,
                            unsigned short* __restrict__ Td) {
  int i = blockIdx.x * 256 + threadIdx.x;
  const float* W; unsigned short* T; int M; int off;
  if (i < 16384)      { W = Wa; T = Ta; M = 128; off = i; }
  else if (i < 32768) { W = Wb; T = Tb; M = 128; off = i - 16384; }
  else if (i < 49152) { W = Wc; T = Tc; M = 128; off = i - 32768; }
  else if (i < 57344) { W = Wd; T = Td; M = 64;  off = i - 49152; }
  else return;
  int k = off / M, m = off - k * M;
  T[m * 128 + k] = f2b(W[off]);
}

// ---------- MFMA GEMM: Y = X[N,128] @ W[128,M] (+bias) [+ el/er] -----------
template<int M, bool AF32>
__global__ __launch_bounds__(256)
void gemm_mfma(const void* __restrict__ Xv,
               const unsigned short* __restrict__ Wt,
               const float* __restrict__ bias,
               const float* __restrict__ al, const float* __restrict__ ar,
               unsigned short* __restrict__ Yb,
               float* __restrict__ el, float* __restrict__ er, int N) {
  constexpr int NT = M / 16;               // 8 (M=128) or 4 (M=64)
  constexpr int H = M / 64;

  const int tid = threadIdx.x;
  const int wave = tid >> 6;
  const int lane = tid & 63;
  const int r = lane & 15;                 // A row / B col / C col
  const int kg = lane >> 4;                // k-group 0..3
  const int rowbase = blockIdx.x * 64 + wave * 16;
  int grow = rowbase + r;
  int growc = grow < N ? grow : N - 1;

  f32x4 acc[NT];
  #pragma unroll
  for (int t = 0; t < NT; ++t) acc[t] = (f32x4){0.f, 0.f, 0.f, 0.f};

  #pragma unroll
  for (int kk = 0; kk < 4; ++kk) {
    const int k0 = kk * 32 + kg * 8;
    bf16x8 a;
    if constexpr (AF32) {
      const float* X = (const float*)Xv;
      const float4* xp =
          reinterpret_cast<const float4*>(X + (size_t)growc * 128 + k0);
      float4 x0 = xp[0], x1 = xp[1];
      a[0] = (short)f2b(x0.x); a[1] = (short)f2b(x0.y);
      a[2] = (short)f2b(x0.z); a[3] = (short)f2b(x0.w);
      a[4] = (short)f2b(x1.x); a[5] = (short)f2b(x1.y);
      a[6] = (short)f2b(x1.z); a[7] = (short)f2b(x1.w);
    } else {
      const unsigned short* Xb = (const unsigned short*)Xv;
      a = *reinterpret_cast<const bf16x8*>(Xb + (size_t)growc * 128 + k0);
    }
    #pragma unroll
    for (int t = 0; t < NT; ++t) {
      bf16x8 b = *reinterpret_cast<const bf16x8*>(
          Wt + (size_t)(t * 16 + r) * 128 + k0);
      acc[t] = __builtin_amdgcn_mfma_f32_16x16x32_bf16(a, b, acc[t], 0, 0, 0);
    }
  }

  float bv[NT];
  #pragma unroll
  for (int t = 0; t < NT; ++t) bv[t] = bias ? bias[t * 16 + r] : 0.f;
  float alv[NT], arv[NT];
  if (al != nullptr) {
    #pragma unroll
    for (int t = 0; t < NT; ++t) {
      alv[t] = al[t * 16 + r];
      arv[t] = ar[t * 16 + r];
    }
  }

  #pragma unroll
  for (int j = 0; j < 4; ++j) {
    int orow = rowbase + kg * 4 + j;       // C row for this (kg, j)
    bool ok = orow < N;
    if (ok) {
      #pragma unroll
      for (int t = 0; t < NT; ++t)
        Yb[(size_t)orow * M + t * 16 + r] = f2b(acc[t][j] + bv[t]);
    }
    if (al != nullptr) {
      float pl0 = 0.f, pr0 = 0.f, pl1 = 0.f, pr1 = 0.f;
      #pragma unroll
      for (int t = 0; t < 4; ++t) {
        pl0 += acc[t][j] * alv[t];
        pr0 += acc[t][j] * arv[t];
      }
      if constexpr (H == 2) {
        #pragma unroll
        for (int t = 4; t < 8; ++t) {
          pl1 += acc[t][j] * alv[t];
          pr1 += acc[t][j] * arv[t];
        }
      }
      #pragma unroll
      for (int off = 1; off < 16; off <<= 1) {   // within 16-lane group
        pl0 += __shfl_xor(pl0, off);
        pr0 += __shfl_xor(pr0, off);
        if constexpr (H == 2) {
          pl1 += __shfl_xor(pl1, off);
          pr1 += __shfl_xor(pr1, off);
        }
      }
      if (r == 0 && ok) {
        if constexpr (H == 2) {
          el[orow * 2 + 0] = pl0; el[orow * 2 + 1] = pl1;
          er[orow * 2 + 0] = pr0; er[orow * 2 + 1] = pr1;
        } else {
          el[orow] = pl0;
          er[orow] = pr0;
        }
      }
    }
  }
}

// ------------------------------ CSR build ----------------------------------
// XCD-class-partitioned count: cnt-line atomics from one XCD only.
__global__ __launch_bounds__(256)
void count_dst(const int* __restrict__ dst, int* __restrict__ cnt, int E) {
  int cls = blockIdx.x & 7;
  int grp = blockIdx.x >> 3;
  int nGrp = gridDim.x >> 3;
  for (int base = grp * 256; base < E; base += nGrp * 256) {
    int i = base + threadIdx.x;
    if (i < E) {
      int d = dst[i];
      if (((d >> 4) & 7) == cls) atomicAdd(&cnt[d], 1);
    }
  }
}

// scan over PADDED counts ((deg+7)&~7) + trip-bin histogram via LDS
__global__ void scan1(const int* __restrict__ cnt, int* __restrict__ outv,
                      int* __restrict__ bsum, int* __restrict__ binCnt,
                      int n) {
  __shared__ int sm[256];
  __shared__ int hist[64];
  int tid = threadIdx.x;
  if (tid < 64) hist[tid] = 0;
  __syncthreads();
  int base = blockIdx.x * 1024 + tid * 4;
  int pre[4];
  int s = 0;
  #pragma unroll
  for (int j = 0; j < 4; ++j) {
    int idx = base + j;
    int c = (idx < n) ? cnt[idx] : 0;
    int v = (idx < n) ? ((c + 7) & ~7) : 0;
    if (idx < n) {
      int t = (c + 7) >> 3; if (t > 63) t = 63;
      atomicAdd(&hist[t], 1);              // LDS atomic (fast)
    }
    pre[j] = s;
    s += v;
  }
  sm[tid] = s;
  __syncthreads();
  for (int off = 1; off < 256; off <<= 1) {
    int a = (tid >= off) ? sm[tid - off] : 0;
    __syncthreads();
    sm[tid] += a;
    __syncthreads();
  }
  int excl = sm[tid] - s;
  #pragma unroll
  for (int j = 0; j < 4; ++j) {
    int idx = base + j;
    if (idx < n) outv[idx] = excl + pre[j];
  }
  if (tid == 255) bsum[blockIdx.x] = sm[255];
  if (tid < 64 && hist[tid] != 0) atomicAdd(&binCnt[tid], hist[tid]);
}

// serial: block-sum scan + 64-bin exclusive scan -> binCur
__global__ void scan2(const int* __restrict__ bsum, int* __restrict__ btop,
                      int nb, int* __restrict__ row_last,
                      const int* __restrict__ binCnt,
                      int* __restrict__ binCur) {
  if (threadIdx.x == 0 && blockIdx.x == 0) {
    int s = 0;
    for (int i = 0; i < nb; ++i) { btop[i] = s; s += bsum[i]; }
    *row_last = s;
    int s2 = 0;
    for (int i = 0; i < 64; ++i) { binCur[i] = s2; s2 += binCnt[i]; }
  }
}

// finalize rp/cur + scatter degree-bucketed node order (wave-aggregated
// atomics: one atomicAdd per distinct bin per wave)
__global__ void scan3(int* __restrict__ rp, int* __restrict__ cur,
                      const int* __restrict__ btop,
                      const int* __restrict__ cnt, int* __restrict__ binCur,
                      int* __restrict__ order, int n) {
  int i = blockIdx.x * blockDim.x + threadIdx.x;
  int lane = threadIdx.x & 63;
  bool live = i < n;
  int t = 0;
  if (live) {
    int v = rp[i] + btop[i >> 10];
    rp[i] = v;
    cur[i] = v;
    int c = cnt[i];
    t = (c + 7) >> 3; if (t > 63) t = 63;
  }
  // wave-aggregated order scatter
  int pos = 0;
  bool done = !live;
  unsigned long long remaining = __ballot(!done);
  while (remaining) {
    int srcl = __ffsll((long long)remaining) - 1;
    int tl = __shfl(t, srcl);
    unsigned long long same = __ballot(!done && t == tl);
    if (!done && t == tl) {
      int lead = __ffsll((long long)same) - 1;
      int cnt_ = __popcll(same);
      int basep = 0;
      if (lane == lead) basep = atomicAdd(&binCur[tl], cnt_);
      basep = __shfl(basep, lead);
      pos = basep + __popcll(same & ((1ull << lane) - 1ull));
      done = true;
    }
    remaining &= ~same;
  }
  if (live) order[pos] = i;
}

// XCD-class-partitioned scatter. After this, cur[node] = real end of run.
__global__ __launch_bounds__(256)
void scatter_edges(const int* __restrict__ src, const int* __restrict__ dst,
                   int* __restrict__ cur, int* __restrict__ s_csr, int E) {
  int cls = blockIdx.x & 7;
  int grp = blockIdx.x >> 3;
  int nGrp = gridDim.x >> 3;
  for (int base = grp * 256; base < E; base += nGrp * 256) {
    int i = base + threadIdx.x;
    if (i < E) {
      int d = dst[i];
      if (((d >> 4) & 7) == cls) {
        int p = atomicAdd(&cur[d], 1);
        s_csr[p] = src[i];
      }
    }
  }
}

// ---- per-node-run edge records: edat[h*EP + p] = (exp(leaky), src) --------
// nodes processed in degree-bucketed order; pad slots get (0,0).
template<int H>
__global__ __launch_bounds__(256)
void edge_prep(const int* __restrict__ s_csr, const float* __restrict__ el,
               const float* __restrict__ er, const int* __restrict__ rp,
               const int* __restrict__ ends, const int* __restrict__ order,
               float2* __restrict__ edat, int N, int EP) {
  int tid = threadIdx.x;
  int g = blockIdx.x * 16 + (tid >> 4);
  int sl = tid & 15;
  if (g >= N) return;
  int node = order[g];
  int beg = rp[node];
  int rend = ends[node];                   // real end
  int pend = rp[node + 1];                 // padded end
  if constexpr (H == 2) {
    float2 re = reinterpret_cast<const float2*>(er)[node];
    for (int p = beg + sl; p < rend; p += 16) {
      int s = s_csr[p];
      float2 le = reinterpret_cast<const float2*>(el)[s];
      float e0 = le.x + re.x;
      float e1 = le.y + re.y;
      e0 = e0 > 0.f ? e0 : SLOPE * e0;
      e1 = e1 > 0.f ? e1 : SLOPE * e1;
      float sb = __int_as_float(s);
      edat[p] = make_float2(__expf(e0), sb);
      edat[(size_t)EP + p] = make_float2(__expf(e1), sb);
    }
    int p2 = rend + sl;
    if (p2 < pend) {                       // pad slots (<=7)
      edat[p2] = make_float2(0.f, __int_as_float(0));
      edat[(size_t)EP + p2] = make_float2(0.f, __int_as_float(0));
    }
  } else {
    float re = er[node];
    for (int p = beg + sl; p < rend; p += 16) {
      int s = s_csr[p];
      float ev = el[s] + re;
      ev = ev > 0.f ? ev : SLOPE * ev;
      edat[p] = make_float2(__expf(ev), __int_as_float(s));
    }
    int p2 = rend + sl;
    if (p2 < pend) edat[p2] = make_float2(0.f, __int_as_float(0));
  }
}

// ------- fused edge-softmax aggregation + bias + elu (branch-free) ---------
// 16-lane group per (sorted-slot, head); runs x8-padded -> no bounds checks.
template<int H, bool SCORE>
__global__ __launch_bounds__(256)
void gat_aggregate(const unsigned short* __restrict__ featb,
                   const float2* __restrict__ edat,
                   const float* __restrict__ bias,
                   const int* __restrict__ row_ptr,
                   const int* __restrict__ order,
                   unsigned short* __restrict__ houtb,
                   const float* __restrict__ Wsc,
                   float* __restrict__ ps, float* __restrict__ pd,
                   int N, int EP) {
  int tid = threadIdx.x;
  int pid = blockIdx.x * 16 + (tid >> 4);  // (slot,head) pair id
  int sl = tid & 15;
  const int NH = N * H;
  bool live = pid < NH;
  int pc = live ? pid : 0;
  int node, head;
  if constexpr (H == 2) { node = order[pc >> 1]; head = pc & 1; }
  else                  { node = order[pc];      head = 0; }
  int beg = live ? row_ptr[node] : 0;
  int end = live ? row_ptr[node + 1] : 0;

  const int rowoff = head * 64 + sl * 4;   // bf16 elem offset within row
  const float2* edath = edat + (size_t)head * EP;

  float4 acc = make_float4(0.f, 0.f, 0.f, 0.f);
  float den = 0.f;

  for (int p = beg; p < end; p += 8) {
    #pragma unroll
    for (int j = 0; j < 8; ++j) {
      float2 ed = edath[p + j];
      float ex = ed.x;
      int s = __float_as_int(ed.y);
      ushort4 u = *reinterpret_cast<const ushort4*>(
          &featb[(size_t)s * (H * 64) + rowoff]);
      den += ex;
      acc.x += ex * b2f(u.x);
      acc.y += ex * b2f(u.y);
      acc.z += ex * b2f(u.z);
      acc.w += ex * b2f(u.w);
    }
  }

  if (live) {
    float inv = 1.f / (den > 0.f ? den : 1.f);
    float4 bv = reinterpret_cast<const float4*>(bias)[head * 16 + sl];
    float4 r;
    r.x = acc.x * inv + bv.x;
    r.y = acc.y * inv + bv.y;
    r.z = acc.z * inv + bv.z;
    r.w = acc.w * inv + bv.w;
    r.x = r.x > 0.f ? r.x : expm1f(r.x);
    r.y = r.y > 0.f ? r.y : expm1f(r.y);
    r.z = r.z > 0.f ? r.z : expm1f(r.z);
    r.w = r.w > 0.f ? r.w : expm1f(r.w);

    if constexpr (!SCORE) {
      ushort4 o;
      o.x = f2b(r.x); o.y = f2b(r.y); o.z = f2b(r.z); o.w = f2b(r.w);
      *reinterpret_cast<ushort4*>(
          &houtb[((size_t)node * H + head) * 64 + sl * 4]) = o;
    } else {
      float s0 = r.x * Wsc[(4 * sl + 0) * 2] + r.y * Wsc[(4 * sl + 1) * 2] +
                 r.z * Wsc[(4 * sl + 2) * 2] + r.w * Wsc[(4 * sl + 3) * 2];
      float s1 = r.x * Wsc[(4 * sl + 0) * 2 + 1] + r.y * Wsc[(4 * sl + 1) * 2 + 1] +
                 r.z * Wsc[(4 * sl + 2) * 2 + 1] + r.w * Wsc[(4 * sl + 3) * 2 + 1];
      float d0 = r.x * Wsc[(64 + 4 * sl + 0) * 2] + r.y * Wsc[(64 + 4 * sl + 1) * 2] +
                 r.z * Wsc[(64 + 4 * sl + 2) * 2] + r.w * Wsc[(64 + 4 * sl + 3) * 2];
      float d1 = r.x * Wsc[(64 + 4 * sl + 0) * 2 + 1] + r.y * Wsc[(64 + 4 * sl + 1) * 2 + 1] +
                 r.z * Wsc[(64 + 4 * sl + 2) * 2 + 1] + r.w * Wsc[(64 + 4 * sl + 3) * 2 + 1];
      #pragma unroll
      for (int off = 1; off < 16; off <<= 1) {   // stays inside 16-lane group
        s0 += __shfl_xor(s0, off);
        s1 += __shfl_xor(s1, off);
        d0 += __shfl_xor(d0, off);
        d1 += __shfl_xor(d1, off);
      }
      if (sl == 0) {
        ps[node * 2 + 0] = s0;
        ps[node * 2 + 1] = s1;
        pd[node * 2 + 0] = d0;
        pd[node * 2 + 1] = d1;
      }
    }
  }
}

// ----------------------- edge scorer output --------------------------------
__global__ void score_out(const int* __restrict__ src,
                          const int* __restrict__ dst,
                          const float* __restrict__ ps,
                          const float* __restrict__ pd,
                          const float* __restrict__ bs,
                          float* __restrict__ out, int E) {
  int i = blockIdx.x * blockDim.x + threadIdx.x;
  if (i < E) {
    int s = src[i], d = dst[i];
    float2 a = *reinterpret_cast<const float2*>(ps + (size_t)s * 2);
    float2 b = *reinterpret_cast<const float2*>(pd + (size_t)d * 2);
    float2 o;
    o.x = a.x + b.x + bs[0];
    o.y = a.y + b.y + bs[1];
    *reinterpret_cast<float2*>(out + (size_t)i * 2) = o;
  }
}

// ---------------------------------------------------------------------------
extern "C" void kernel_launch(void* const* d_in, const int* in_sizes, int n_in,
                              void* d_out, int out_size, void* d_ws,
                              size_t ws_size, hipStream_t stream) {
  const float* x    = (const float*)d_in[0];
  const int*   src  = (const int*)d_in[1];
  const int*   dst  = (const int*)d_in[2];
  const float* Wemb = (const float*)d_in[3];
  const float* bemb = (const float*)d_in[4];
  const float* W0   = (const float*)d_in[5];
  const float* al0  = (const float*)d_in[6];
  const float* ar0  = (const float*)d_in[7];
  const float* b0   = (const float*)d_in[8];
  const float* W1   = (const float*)d_in[9];
  const float* al1  = (const float*)d_in[10];
  const float* ar1  = (const float*)d_in[11];
  const float* b1   = (const float*)d_in[12];
  const float* W2   = (const float*)d_in[13];
  const float* al2  = (const float*)d_in[14];
  const float* ar2  = (const float*)d_in[15];
  const float* b2   = (const float*)d_in[16];
  const float* Wsc  = (const float*)d_in[17];
  const float* bsc  = (const float*)d_in[18];

  const int N = in_sizes[0] / 128;
  const int E = in_sizes[1];
  float* out = (float*)d_out;
  const int EP = E + 7 * N + 8;            // upper bound on padded edge count

  // workspace carve-up (16B-aligned buffers first)
  char* w = (char*)d_ws;
  float2* edat = (float2*)w; w += (size_t)EP * 2 * 8;    // per-head (ex, src)
  unsigned short* Ab = (unsigned short*)w; w += (size_t)N * 128 * 2; // bf16 h
  unsigned short* Bb = (unsigned short*)w; w += (size_t)N * 128 * 2; // bf16 feat
  unsigned short* WembT = (unsigned short*)w; w += 128 * 128 * 2;
  unsigned short* W0T   = (unsigned short*)w; w += 128 * 128 * 2;
  unsigned short* W1T   = (unsigned short*)w; w += 128 * 128 * 2;
  unsigned short* W2T   = (unsigned short*)w; w += 128 * 64 * 2;
  float* el  = (float*)w; w += (size_t)N * 2 * 4;
  float* er  = (float*)w; w += (size_t)N * 2 * 4;
  float* ps  = (float*)w; w += (size_t)N * 2 * 4;
  float* pd  = (float*)w; w += (size_t)N * 2 * 4;
  int* s_csr = (int*)w;   w += (size_t)EP * 4;
  int* cnt   = (int*)w;   w += (size_t)N * 4;
  int* binCnt = (int*)w;  w += 64 * 4;                   // memset with cnt
  int* rp    = (int*)w;   w += (size_t)(N + 4) * 4;
  int* cur   = (int*)w;   w += (size_t)N * 4;
  int* order = (int*)w;   w += (size_t)N * 4;
  int* binCur = (int*)w;  w += 64 * 4;
  int* bsum  = (int*)w;   w += 4096;
  int* btop  = (int*)w;   w += 4096;

  // ---- weight prep (bf16 transposed, one dispatch) ----
  prep_wt_all<<<(57344 + 255) / 256, 256, 0, stream>>>(
      Wemb, W0, W1, W2, WembT, W0T, W1T, W2T);

  // ---- CSR build (by dst), x8-padded runs + degree-bucketed order ----
  hipMemsetAsync(cnt, 0, (size_t)N * 4 + 64 * 4, stream);  // cnt + binCnt
  count_dst<<<2048, 256, 0, stream>>>(dst, cnt, E);
  int nb = (N + 1023) / 1024;
  scan1<<<nb, 256, 0, stream>>>(cnt, rp, bsum, binCnt, N);
  scan2<<<1, 64, 0, stream>>>(bsum, btop, nb, rp + N, binCnt, binCur);
  scan3<<<(N + 255) / 256, 256, 0, stream>>>(rp, cur, btop, cnt, binCur,
                                             order, N);
  scatter_edges<<<2048, 256, 0, stream>>>(src, dst, cur, s_csr, E);

  const int gb = (N + 63) / 64;        // MFMA GEMM blocks (64 rows each)
  const int nbk = (N + 15) / 16;       // per-node-run kernels
  const int pb2 = (N * 2 + 15) / 16;   // pair blocks, H=2
  const int pb1 = (N * 1 + 15) / 16;

  // ---- embedding: x(fp32) @ Wemb + bemb -> Ab (bf16) ----
  gemm_mfma<128, true><<<gb, 256, 0, stream>>>(x, WembT, bemb, nullptr,
                                               nullptr, Ab, nullptr, nullptr,
                                               N);

  // ---- GAT layer 0 ----
  gemm_mfma<128, false><<<gb, 256, 0, stream>>>(Ab, W0T, nullptr, al0, ar0,
                                                Bb, el, er, N);
  edge_prep<2><<<nbk, 256, 0, stream>>>(s_csr, el, er, rp, cur, order, edat,
                                        N, EP);
  gat_aggregate<2, false><<<pb2, 256, 0, stream>>>(Bb, edat, b0, rp, order,
                                                   Ab, nullptr, nullptr,
                                                   nullptr, N, EP);
  // ---- GAT layer 1 ----
  gemm_mfma<128, false><<<gb, 256, 0, stream>>>(Ab, W1T, nullptr, al1, ar1,
                                                Bb, el, er, N);
  edge_prep<2><<<nbk, 256, 0, stream>>>(s_csr, el, er, rp, cur, order, edat,
                                        N, EP);
  gat_aggregate<2, false><<<pb2, 256, 0, stream>>>(Bb, edat, b1, rp, order,
                                                   Ab, nullptr, nullptr,
                                                   nullptr, N, EP);
  // ---- GAT layer 2 (1 head) + fused scorer partials ----
  gemm_mfma<64, false><<<gb, 256, 0, stream>>>(Ab, W2T, nullptr, al2, ar2,
                                               Bb, el, er, N);
  edge_prep<1><<<nbk, 256, 0, stream>>>(s_csr, el, er, rp, cur, order, edat,
                                        N, EP);
  gat_aggregate<1, true><<<pb1, 256, 0, stream>>>(Bb, edat, b2, rp, order,
                                                  nullptr, Wsc, ps, pd,
                                                  N, EP);

  // ---- edge scorer output ----
  score_out<<<(E + 255) / 256, 256, 0, stream>>>(src, dst, ps, pd, bsc, out, E);
}

// Round 15
// 392.093 us; speedup vs baseline: 2.0279x; 1.0700x over previous
//
#include <hip/hip_runtime.h>
#include <hip/hip_bf16.h>
#include <math.h>

// ---------------------------------------------------------------------------
// GAT edge classifier. Pipeline per call:
//   weight prep (1 kernel, fp32 W -> bf16 W^T), CSR build with 8-padded runs
//   (count/scan/XCD-class scatter), emb MFMA-GEMM -> 3x [ MFMA-GEMM(+el/er)
//   -> edge_prep(real+pad records) -> branch-free aggregate ] -> score_out
// h is bf16 at every inter-layer boundary; all accumulation fp32.
// Node runs padded to x8 with (ex=0,s=0) records: aggregate inner loop has
// NO bounds checks; pad gathers hit feat row 0 (L1-hot); den/acc exact.
// [R14 lesson: degree-bucketed node order regressed -25us (scattered hout
//  writes + order[] indirection beat the ~10% exec-mask saving) - reverted.]
// ---------------------------------------------------------------------------

constexpr float SLOPE = 0.2f;

typedef __attribute__((ext_vector_type(8))) short bf16x8;
typedef __attribute__((ext_vector_type(4))) float f32x4;

__device__ __forceinline__ float b2f(unsigned short u) {
  union { unsigned int i; float f; } v;
  v.i = ((unsigned int)u) << 16;
  return v.f;
}
__device__ __forceinline__ unsigned short f2b(float f) {
  unsigned int x = __float_as_uint(f);
  unsigned int r = (x + 0x7fffu + ((x >> 16) & 1u)) >> 16;   // RNE
  return (unsigned short)r;
}

// ---- weight prep: 4 matrices W[K=128][M] fp32 -> Wt[M][128] bf16, fused ---
__global__ void prep_wt_all(const float* __restrict__ Wa,
                            const float* __restrict__ Wb,
                            const float* __restrict__ Wc,
                            const float* __restrict__ Wd,
                            unsigned short* __restrict__ Ta,
                            unsigned short* __restrict__ Tb,
                            unsigned short* __restrict__ Tc,
                            unsigned short* __restrict__ Td) {
  int i = blockIdx.x * 256 + threadIdx.x;
  const float* W; unsigned short* T; int M; int off;
  if (i < 16384)      { W = Wa; T = Ta; M = 128; off = i; }
  else if (i < 32768) { W = Wb; T = Tb; M = 128; off = i - 16384; }
  else if (i < 49152) { W = Wc; T = Tc; M = 128; off = i - 32768; }
  else if (i < 57344) { W = Wd; T = Td; M = 64;  off = i - 49152; }
  else return;
  int k = off / M, m = off - k * M;
  T[m * 128 + k] = f2b(W[off]);
}

// ---------- MFMA GEMM: Y = X[N,128] @ W[128,M] (+bias) [+ el/er] -----------
// block = 256 thr = 4 waves; wave owns 16 rows x M cols. A-frags direct from
// global; B-frags from Wt (L1-hot). Output bf16.
// C/D layout: col=lane&15, row=(lane>>4)*4+reg  [m89-verified].
template<int M, bool AF32>
__global__ __launch_bounds__(256)
void gemm_mfma(const void* __restrict__ Xv,
               const unsigned short* __restrict__ Wt,
               const float* __restrict__ bias,
               const float* __restrict__ al, const float* __restrict__ ar,
               unsigned short* __restrict__ Yb,
               float* __restrict__ el, float* __restrict__ er, int N) {
  constexpr int NT = M / 16;               // 8 (M=128) or 4 (M=64)
  constexpr int H = M / 64;

  const int tid = threadIdx.x;
  const int wave = tid >> 6;
  const int lane = tid & 63;
  const int r = lane & 15;                 // A row / B col / C col
  const int kg = lane >> 4;                // k-group 0..3
  const int rowbase = blockIdx.x * 64 + wave * 16;
  int grow = rowbase + r;
  int growc = grow < N ? grow : N - 1;

  f32x4 acc[NT];
  #pragma unroll
  for (int t = 0; t < NT; ++t) acc[t] = (f32x4){0.f, 0.f, 0.f, 0.f};

  #pragma unroll
  for (int kk = 0; kk < 4; ++kk) {
    const int k0 = kk * 32 + kg * 8;
    bf16x8 a;
    if constexpr (AF32) {
      const float* X = (const float*)Xv;
      const float4* xp =
          reinterpret_cast<const float4*>(X + (size_t)growc * 128 + k0);
      float4 x0 = xp[0], x1 = xp[1];
      a[0] = (short)f2b(x0.x); a[1] = (short)f2b(x0.y);
      a[2] = (short)f2b(x0.z); a[3] = (short)f2b(x0.w);
      a[4] = (short)f2b(x1.x); a[5] = (short)f2b(x1.y);
      a[6] = (short)f2b(x1.z); a[7] = (short)f2b(x1.w);
    } else {
      const unsigned short* Xb = (const unsigned short*)Xv;
      a = *reinterpret_cast<const bf16x8*>(Xb + (size_t)growc * 128 + k0);
    }
    #pragma unroll
    for (int t = 0; t < NT; ++t) {
      bf16x8 b = *reinterpret_cast<const bf16x8*>(
          Wt + (size_t)(t * 16 + r) * 128 + k0);
      acc[t] = __builtin_amdgcn_mfma_f32_16x16x32_bf16(a, b, acc[t], 0, 0, 0);
    }
  }

  float bv[NT];
  #pragma unroll
  for (int t = 0; t < NT; ++t) bv[t] = bias ? bias[t * 16 + r] : 0.f;
  float alv[NT], arv[NT];
  if (al != nullptr) {
    #pragma unroll
    for (int t = 0; t < NT; ++t) {
      alv[t] = al[t * 16 + r];
      arv[t] = ar[t * 16 + r];
    }
  }

  #pragma unroll
  for (int j = 0; j < 4; ++j) {
    int orow = rowbase + kg * 4 + j;       // C row for this (kg, j)
    bool ok = orow < N;
    if (ok) {
      #pragma unroll
      for (int t = 0; t < NT; ++t)
        Yb[(size_t)orow * M + t * 16 + r] = f2b(acc[t][j] + bv[t]);
    }
    if (al != nullptr) {
      float pl0 = 0.f, pr0 = 0.f, pl1 = 0.f, pr1 = 0.f;
      #pragma unroll
      for (int t = 0; t < 4; ++t) {
        pl0 += acc[t][j] * alv[t];
        pr0 += acc[t][j] * arv[t];
      }
      if constexpr (H == 2) {
        #pragma unroll
        for (int t = 4; t < 8; ++t) {
          pl1 += acc[t][j] * alv[t];
          pr1 += acc[t][j] * arv[t];
        }
      }
      #pragma unroll
      for (int off = 1; off < 16; off <<= 1) {   // within 16-lane group
        pl0 += __shfl_xor(pl0, off);
        pr0 += __shfl_xor(pr0, off);
        if constexpr (H == 2) {
          pl1 += __shfl_xor(pl1, off);
          pr1 += __shfl_xor(pr1, off);
        }
      }
      if (r == 0 && ok) {
        if constexpr (H == 2) {
          el[orow * 2 + 0] = pl0; el[orow * 2 + 1] = pl1;
          er[orow * 2 + 0] = pr0; er[orow * 2 + 1] = pr1;
        } else {
          el[orow] = pl0;
          er[orow] = pr0;
        }
      }
    }
  }
}

// ------------------------------ CSR build ----------------------------------
// XCD-class-partitioned count: cnt-line atomics from one XCD only.
__global__ __launch_bounds__(256)
void count_dst(const int* __restrict__ dst, int* __restrict__ cnt, int E) {
  int cls = blockIdx.x & 7;
  int grp = blockIdx.x >> 3;
  int nGrp = gridDim.x >> 3;
  for (int base = grp * 256; base < E; base += nGrp * 256) {
    int i = base + threadIdx.x;
    if (i < E) {
      int d = dst[i];
      if (((d >> 4) & 7) == cls) atomicAdd(&cnt[d], 1);
    }
  }
}

// scan over PADDED counts: run length for node = (deg+7)&~7
__global__ void scan1(const int* __restrict__ cnt, int* __restrict__ outv,
                      int* __restrict__ bsum, int n) {
  __shared__ int sm[256];
  int tid = threadIdx.x;
  int base = blockIdx.x * 1024 + tid * 4;
  int pre[4];
  int s = 0;
  #pragma unroll
  for (int j = 0; j < 4; ++j) {
    int idx = base + j;
    int v = (idx < n) ? ((cnt[idx] + 7) & ~7) : 0;
    pre[j] = s;
    s += v;
  }
  sm[tid] = s;
  __syncthreads();
  for (int off = 1; off < 256; off <<= 1) {
    int a = (tid >= off) ? sm[tid - off] : 0;
    __syncthreads();
    sm[tid] += a;
    __syncthreads();
  }
  int excl = sm[tid] - s;
  #pragma unroll
  for (int j = 0; j < 4; ++j) {
    int idx = base + j;
    if (idx < n) outv[idx] = excl + pre[j];
  }
  if (tid == 255) bsum[blockIdx.x] = sm[255];
}

__global__ void scan2(const int* __restrict__ bsum, int* __restrict__ btop,
                      int nb, int* __restrict__ row_last) {
  if (threadIdx.x == 0 && blockIdx.x == 0) {
    int s = 0;
    for (int i = 0; i < nb; ++i) { btop[i] = s; s += bsum[i]; }
    *row_last = s;
  }
}

__global__ void scan3(int* __restrict__ rp, int* __restrict__ cur,
                      const int* __restrict__ btop, int n) {
  int i = blockIdx.x * blockDim.x + threadIdx.x;
  if (i < n) {
    int v = rp[i] + btop[i >> 10];
    rp[i] = v;
    cur[i] = v;
  }
}

// XCD-class-partitioned scatter (round-9 win). After this, cur[node] = real
// end of node's run (rp[node] + deg[node]).
__global__ __launch_bounds__(256)
void scatter_edges(const int* __restrict__ src, const int* __restrict__ dst,
                   int* __restrict__ cur, int* __restrict__ s_csr, int E) {
  int cls = blockIdx.x & 7;
  int grp = blockIdx.x >> 3;
  int nGrp = gridDim.x >> 3;
  for (int base = grp * 256; base < E; base += nGrp * 256) {
    int i = base + threadIdx.x;
    if (i < E) {
      int d = dst[i];
      if (((d >> 4) & 7) == cls) {
        int p = atomicAdd(&cur[d], 1);
        s_csr[p] = src[i];
      }
    }
  }
}

// ---- per-node-run edge records: edat[h*EP + p] = (exp(leaky), src) --------
// 16 lanes per node walk its run; writes (0,0) into the <=7 pad slots.
template<int H>
__global__ __launch_bounds__(256)
void edge_prep(const int* __restrict__ s_csr, const float* __restrict__ el,
               const float* __restrict__ er, const int* __restrict__ rp,
               const int* __restrict__ ends, float2* __restrict__ edat,
               int N, int EP) {
  int tid = threadIdx.x;
  int node = blockIdx.x * 16 + (tid >> 4);
  int sl = tid & 15;
  if (node >= N) return;
  int beg = rp[node];
  int rend = ends[node];                   // real end
  int pend = rp[node + 1];                 // padded end
  if constexpr (H == 2) {
    float2 re = reinterpret_cast<const float2*>(er)[node];
    for (int p = beg + sl; p < rend; p += 16) {
      int s = s_csr[p];
      float2 le = reinterpret_cast<const float2*>(el)[s];
      float e0 = le.x + re.x;
      float e1 = le.y + re.y;
      e0 = e0 > 0.f ? e0 : SLOPE * e0;
      e1 = e1 > 0.f ? e1 : SLOPE * e1;
      float sb = __int_as_float(s);
      edat[p] = make_float2(__expf(e0), sb);
      edat[(size_t)EP + p] = make_float2(__expf(e1), sb);
    }
    int p2 = rend + sl;
    if (p2 < pend) {                       // pad slots (<=7)
      edat[p2] = make_float2(0.f, __int_as_float(0));
      edat[(size_t)EP + p2] = make_float2(0.f, __int_as_float(0));
    }
  } else {
    float re = er[node];
    for (int p = beg + sl; p < rend; p += 16) {
      int s = s_csr[p];
      float ev = el[s] + re;
      ev = ev > 0.f ? ev : SLOPE * ev;
      edat[p] = make_float2(__expf(ev), __int_as_float(s));
    }
    int p2 = rend + sl;
    if (p2 < pend) edat[p2] = make_float2(0.f, __int_as_float(0));
  }
}

// ------- fused edge-softmax aggregation + bias + elu (branch-free) ---------
// 16-lane group per (node,head); runs are x8-padded so the inner loop has no
// bounds checks. bf16 gathers, fp32 accum, bf16 out.
template<int H, bool SCORE>
__global__ __launch_bounds__(256)
void gat_aggregate(const unsigned short* __restrict__ featb,
                   const float2* __restrict__ edat,
                   const float* __restrict__ bias,
                   const int* __restrict__ row_ptr,
                   unsigned short* __restrict__ houtb,
                   const float* __restrict__ Wsc,
                   float* __restrict__ ps, float* __restrict__ pd,
                   int N, int EP) {
  int tid = threadIdx.x;
  int pid = blockIdx.x * 16 + (tid >> 4);  // (node,head) pair id
  int sl = tid & 15;
  const int NH = N * H;
  bool live = pid < NH;
  int pc = live ? pid : 0;
  int node, head;
  if constexpr (H == 2) { node = pc >> 1; head = pc & 1; }
  else                  { node = pc;      head = 0; }
  int beg = live ? row_ptr[node] : 0;
  int end = live ? row_ptr[node + 1] : 0;

  const int rowoff = head * 64 + sl * 4;   // bf16 elem offset within row
  const float2* edath = edat + (size_t)head * EP;

  float4 acc = make_float4(0.f, 0.f, 0.f, 0.f);
  float den = 0.f;

  for (int p = beg; p < end; p += 8) {
    #pragma unroll
    for (int j = 0; j < 8; ++j) {
      float2 ed = edath[p + j];
      float ex = ed.x;
      int s = __float_as_int(ed.y);
      ushort4 u = *reinterpret_cast<const ushort4*>(
          &featb[(size_t)s * (H * 64) + rowoff]);
      den += ex;
      acc.x += ex * b2f(u.x);
      acc.y += ex * b2f(u.y);
      acc.z += ex * b2f(u.z);
      acc.w += ex * b2f(u.w);
    }
  }

  if (live) {
    float inv = 1.f / (den > 0.f ? den : 1.f);
    float4 bv = reinterpret_cast<const float4*>(bias)[head * 16 + sl];
    float4 r;
    r.x = acc.x * inv + bv.x;
    r.y = acc.y * inv + bv.y;
    r.z = acc.z * inv + bv.z;
    r.w = acc.w * inv + bv.w;
    r.x = r.x > 0.f ? r.x : expm1f(r.x);
    r.y = r.y > 0.f ? r.y : expm1f(r.y);
    r.z = r.z > 0.f ? r.z : expm1f(r.z);
    r.w = r.w > 0.f ? r.w : expm1f(r.w);

    if constexpr (!SCORE) {
      ushort4 o;
      o.x = f2b(r.x); o.y = f2b(r.y); o.z = f2b(r.z); o.w = f2b(r.w);
      *reinterpret_cast<ushort4*>(&houtb[(size_t)pid * 64 + sl * 4]) = o;
    } else {
      float s0 = r.x * Wsc[(4 * sl + 0) * 2] + r.y * Wsc[(4 * sl + 1) * 2] +
                 r.z * Wsc[(4 * sl + 2) * 2] + r.w * Wsc[(4 * sl + 3) * 2];
      float s1 = r.x * Wsc[(4 * sl + 0) * 2 + 1] + r.y * Wsc[(4 * sl + 1) * 2 + 1] +
                 r.z * Wsc[(4 * sl + 2) * 2 + 1] + r.w * Wsc[(4 * sl + 3) * 2 + 1];
      float d0 = r.x * Wsc[(64 + 4 * sl + 0) * 2] + r.y * Wsc[(64 + 4 * sl + 1) * 2] +
                 r.z * Wsc[(64 + 4 * sl + 2) * 2] + r.w * Wsc[(64 + 4 * sl + 3) * 2];
      float d1 = r.x * Wsc[(64 + 4 * sl + 0) * 2 + 1] + r.y * Wsc[(64 + 4 * sl + 1) * 2 + 1] +
                 r.z * Wsc[(64 + 4 * sl + 2) * 2 + 1] + r.w * Wsc[(64 + 4 * sl + 3) * 2 + 1];
      #pragma unroll
      for (int off = 1; off < 16; off <<= 1) {   // stays inside 16-lane group
        s0 += __shfl_xor(s0, off);
        s1 += __shfl_xor(s1, off);
        d0 += __shfl_xor(d0, off);
        d1 += __shfl_xor(d1, off);
      }
      if (sl == 0) {
        ps[node * 2 + 0] = s0;
        ps[node * 2 + 1] = s1;
        pd[node * 2 + 0] = d0;
        pd[node * 2 + 1] = d1;
      }
    }
  }
}

// ----------------------- edge scorer output --------------------------------
__global__ void score_out(const int* __restrict__ src,
                          const int* __restrict__ dst,
                          const float* __restrict__ ps,
                          const float* __restrict__ pd,
                          const float* __restrict__ bs,
                          float* __restrict__ out, int E) {
  int i = blockIdx.x * blockDim.x + threadIdx.x;
  if (i < E) {
    int s = src[i], d = dst[i];
    float2 a = *reinterpret_cast<const float2*>(ps + (size_t)s * 2);
    float2 b = *reinterpret_cast<const float2*>(pd + (size_t)d * 2);
    float2 o;
    o.x = a.x + b.x + bs[0];
    o.y = a.y + b.y + bs[1];
    *reinterpret_cast<float2*>(out + (size_t)i * 2) = o;
  }
}

// ---------------------------------------------------------------------------
extern "C" void kernel_launch(void* const* d_in, const int* in_sizes, int n_in,
                              void* d_out, int out_size, void* d_ws,
                              size_t ws_size, hipStream_t stream) {
  const float* x    = (const float*)d_in[0];
  const int*   src  = (const int*)d_in[1];
  const int*   dst  = (const int*)d_in[2];
  const float* Wemb = (const float*)d_in[3];
  const float* bemb = (const float*)d_in[4];
  const float* W0   = (const float*)d_in[5];
  const float* al0  = (const float*)d_in[6];
  const float* ar0  = (const float*)d_in[7];
  const float* b0   = (const float*)d_in[8];
  const float* W1   = (const float*)d_in[9];
  const float* al1  = (const float*)d_in[10];
  const float* ar1  = (const float*)d_in[11];
  const float* b1   = (const float*)d_in[12];
  const float* W2   = (const float*)d_in[13];
  const float* al2  = (const float*)d_in[14];
  const float* ar2  = (const float*)d_in[15];
  const float* b2   = (const float*)d_in[16];
  const float* Wsc  = (const float*)d_in[17];
  const float* bsc  = (const float*)d_in[18];

  const int N = in_sizes[0] / 128;
  const int E = in_sizes[1];
  float* out = (float*)d_out;
  const int EP = E + 7 * N + 8;            // upper bound on padded edge count

  // workspace carve-up (16B-aligned buffers first)
  char* w = (char*)d_ws;
  float2* edat = (float2*)w; w += (size_t)EP * 2 * 8;    // per-head (ex, src)
  unsigned short* Ab = (unsigned short*)w; w += (size_t)N * 128 * 2; // bf16 h
  unsigned short* Bb = (unsigned short*)w; w += (size_t)N * 128 * 2; // bf16 feat
  unsigned short* WembT = (unsigned short*)w; w += 128 * 128 * 2;
  unsigned short* W0T   = (unsigned short*)w; w += 128 * 128 * 2;
  unsigned short* W1T   = (unsigned short*)w; w += 128 * 128 * 2;
  unsigned short* W2T   = (unsigned short*)w; w += 128 * 64 * 2;
  float* el  = (float*)w; w += (size_t)N * 2 * 4;
  float* er  = (float*)w; w += (size_t)N * 2 * 4;
  float* ps  = (float*)w; w += (size_t)N * 2 * 4;
  float* pd  = (float*)w; w += (size_t)N * 2 * 4;
  int* s_csr = (int*)w;   w += (size_t)EP * 4;
  int* cnt   = (int*)w;   w += (size_t)N * 4;
  int* rp    = (int*)w;   w += (size_t)(N + 4) * 4;
  int* cur   = (int*)w;   w += (size_t)N * 4;
  int* bsum  = (int*)w;   w += 4096;
  int* btop  = (int*)w;   w += 4096;

  // ---- weight prep (bf16 transposed, one dispatch) ----
  prep_wt_all<<<(57344 + 255) / 256, 256, 0, stream>>>(
      Wemb, W0, W1, W2, WembT, W0T, W1T, W2T);

  // ---- CSR build (by dst), x8-padded runs ----
  hipMemsetAsync(cnt, 0, (size_t)N * 4, stream);
  count_dst<<<2048, 256, 0, stream>>>(dst, cnt, E);
  int nb = (N + 1023) / 1024;
  scan1<<<nb, 256, 0, stream>>>(cnt, rp, bsum, N);
  scan2<<<1, 64, 0, stream>>>(bsum, btop, nb, rp + N);
  scan3<<<(N + 255) / 256, 256, 0, stream>>>(rp, cur, btop, N);
  scatter_edges<<<2048, 256, 0, stream>>>(src, dst, cur, s_csr, E);

  const int gb = (N + 63) / 64;        // MFMA GEMM blocks (64 rows each)
  const int nbk = (N + 15) / 16;       // per-node-run kernels
  const int pb2 = (N * 2 + 15) / 16;   // pair blocks, H=2
  const int pb1 = (N * 1 + 15) / 16;

  // ---- embedding: x(fp32) @ Wemb + bemb -> Ab (bf16) ----
  gemm_mfma<128, true><<<gb, 256, 0, stream>>>(x, WembT, bemb, nullptr,
                                               nullptr, Ab, nullptr, nullptr,
                                               N);

  // ---- GAT layer 0 ----
  gemm_mfma<128, false><<<gb, 256, 0, stream>>>(Ab, W0T, nullptr, al0, ar0,
                                                Bb, el, er, N);
  edge_prep<2><<<nbk, 256, 0, stream>>>(s_csr, el, er, rp, cur, edat, N, EP);
  gat_aggregate<2, false><<<pb2, 256, 0, stream>>>(Bb, edat, b0, rp, Ab,
                                                   nullptr, nullptr, nullptr,
                                                   N, EP);
  // ---- GAT layer 1 ----
  gemm_mfma<128, false><<<gb, 256, 0, stream>>>(Ab, W1T, nullptr, al1, ar1,
                                                Bb, el, er, N);
  edge_prep<2><<<nbk, 256, 0, stream>>>(s_csr, el, er, rp, cur, edat, N, EP);
  gat_aggregate<2, false><<<pb2, 256, 0, stream>>>(Bb, edat, b1, rp, Ab,
                                                   nullptr, nullptr, nullptr,
                                                   N, EP);
  // ---- GAT layer 2 (1 head) + fused scorer partials ----
  gemm_mfma<64, false><<<gb, 256, 0, stream>>>(Ab, W2T, nullptr, al2, ar2,
                                               Bb, el, er, N);
  edge_prep<1><<<nbk, 256, 0, stream>>>(s_csr, el, er, rp, cur, edat, N, EP);
  gat_aggregate<1, true><<<pb1, 256, 0, stream>>>(Bb, edat, b2, rp, nullptr,
                                                  Wsc, ps, pd, N, EP);

  // ---- edge scorer output ----
  score_out<<<(E + 255) / 256, 256, 0, stream>>>(src, dst, ps, pd, bsc, out, E);
}